// Round 13
// baseline (247.259 us; speedup 1.0000x reference)
//
#include <hip/hip_runtime.h>

#define N_NODES 50000
#define N_EDGES 800000
#define N_LABEL 200000
#define ROW_BLOCKS 782   // ceil(50000/64)

typedef __attribute__((ext_vector_type(4))) float f32x4;
typedef _Float16 f16;
typedef __attribute__((ext_vector_type(8))) _Float16 f16x8;

// ---------------- zero cnt+cnt2 ----------------
__global__ __launch_bounds__(256)
void k_zero(int4* __restrict__ p, int n4) {
    int i = blockIdx.x * 256 + threadIdx.x;
    if (i < n4) p[i] = int4{0, 0, 0, 0};
}

// ---------------- prep: W transpose/split fp16 hi+lo | XCD-partitioned deg_count ----------
__global__ __launch_bounds__(256)
void k_prep(const float* __restrict__ W1, const float* __restrict__ W2,
            const float* __restrict__ W3,
            f16* WT1h, f16* WT1l, f16* WT2h, f16* WT2l, f16* WT3h, f16* WT3l,
            const int* __restrict__ dst, int* cnt) {
    int b = blockIdx.x, tid = threadIdx.x;
    if (b < 64) {
        int t = b * 256 + tid;                 // < 16384
        int c = t >> 7, k = t & 127;
        float w = W1[k * 128 + c];
        f16 h = (f16)w;
        WT1h[c * 128 + k] = h; WT1l[c * 128 + k] = (f16)(w - (float)h);
        w = W2[k * 128 + c];
        h = (f16)w;
        WT2h[c * 128 + k] = h; WT2l[c * 128 + k] = (f16)(w - (float)h);
        if (c < 64) {
            w = W3[k * 64 + c];
            h = (f16)w;
            WT3h[c * 128 + k] = h; WT3l[c * 128 + k] = (f16)(w - (float)h);
        }
    } else {
        int vb = b - 64;                       // [0, 25000)
        int g = vb & 7;
        int i = (vb >> 3) * 256 + tid;         // < 800,000 exactly
        int d = dst[i];
        if ((unsigned)(d - g * 6250) < 6250u) atomicAdd(&cnt[d], 1);
    }
}

// ---------------- scan chain ----------------
__global__ __launch_bounds__(256)
void k_partial(const int* __restrict__ cnt, float* __restrict__ dinv,
               int* __restrict__ bsum, int N) {
    __shared__ int wsum[4];
    int b = blockIdx.x, t = threadIdx.x;
    int i = b * 256 + t;
    int v = (i < N) ? cnt[i] : 0;
    if (i < N) dinv[i] = rsqrtf((float)v + 1.0f);
    int s = v;
#pragma unroll
    for (int d = 1; d < 64; d <<= 1) s += __shfl_xor(s, d, 64);
    if ((t & 63) == 0) wsum[t >> 6] = s;
    __syncthreads();
    if (t == 0) bsum[b] = wsum[0] + wsum[1] + wsum[2] + wsum[3];
}

__global__ __launch_bounds__(256)
void k_offsets(const int* __restrict__ cnt, const int* __restrict__ bsum,
               int* __restrict__ off, int N, int NB) {
    __shared__ int wsum[4];
    __shared__ int add0_s;
    int b = blockIdx.x, t = threadIdx.x;
    int v0 = (t < b && t < NB) ? bsum[t] : 0;
    int s0 = v0;
#pragma unroll
    for (int d = 1; d < 64; d <<= 1) s0 += __shfl_xor(s0, d, 64);
    if ((t & 63) == 0) wsum[t >> 6] = s0;
    __syncthreads();
    if (t == 0) add0_s = wsum[0] + wsum[1] + wsum[2] + wsum[3];
    __syncthreads();
    int add = add0_s;
    __syncthreads();
    int i = b * 256 + t;
    int v = (i < N) ? cnt[i] : 0;
    int lane = t & 63, w = t >> 6;
    int sv = v;
#pragma unroll
    for (int d = 1; d < 64; d <<= 1) {
        int u = __shfl_up(sv, d, 64);
        if (lane >= d) sv += u;
    }
    if (lane == 63) wsum[w] = sv;
    __syncthreads();
    for (int ww = 0; ww < w; ++ww) add += wsum[ww];
    if (i < N) off[i + 1] = add + sv;
    if (i == 0) off[0] = 0;
}

// ---------------- XCD-partitioned bucket fill ----------------
__global__ __launch_bounds__(256)
void k_bucket(const int* __restrict__ srcv, const int* __restrict__ dstv,
              const int* __restrict__ off, int* cnt2, unsigned short* __restrict__ csr) {
    int vb = blockIdx.x;
    int g = vb & 7;
    int i = (vb >> 3) * 256 + threadIdx.x;   // < 800,000 exactly
    int d = dstv[i];
    if ((unsigned)(d - g * 6250) < 6250u) {
        int slot = off[d] + atomicAdd(&cnt2[d], 1);
        csr[slot] = (unsigned short)srcv[i];
    }
}

// ---------------- GEMM layer 1: fp32 x, in-register fp16 split, W in LDS ----------------
__global__ __launch_bounds__(256)
void k_gemm1(const float* __restrict__ x,
             const f16* __restrict__ WTh, const f16* __restrict__ WTl,
             const float* __restrict__ dinv, f16* __restrict__ A, int N) {
    constexpr int M = 128, NCB = 4;
    __shared__ f16 Hs[64 * 136];
    __shared__ f16 Ls[64 * 136];
    int b = blockIdx.x;
    int c0 = (b & 1) * 64;
    int t = threadIdx.x;

#pragma unroll
    for (int i = 0; i < 4; ++i) {
        int ch = t + i * 256;
        int col = ch >> 4;
        int kc = (ch & 15) * 8;
        *(f16x8*)&Hs[col * 136 + kc] = *(const f16x8*)&WTh[(long)(c0 + col) * 128 + kc];
        *(f16x8*)&Ls[col * 136 + kc] = *(const f16x8*)&WTl[(long)(c0 + col) * 128 + kc];
    }

    int wv = t >> 6, l = t & 63;
    int r0w = (b >> 1) * 64 + wv * 16;
    int arow = r0w + (l & 15);
    if (arow >= N) arow = N - 1;
    int kb = (l >> 4) * 8;

    f16x8 ah[4], al[4];
#pragma unroll
    for (int ks = 0; ks < 4; ++ks) {
        const float* xp = &x[(long)arow * 128 + ks * 32 + kb];
        float4 a0 = *(const float4*)xp;
        float4 a1 = *(const float4*)(xp + 4);
        float fv[8] = {a0.x, a0.y, a0.z, a0.w, a1.x, a1.y, a1.z, a1.w};
#pragma unroll
        for (int j = 0; j < 8; ++j) {
            f16 h = (f16)fv[j];
            ah[ks][j] = h;
            al[ks][j] = (f16)(fv[j] - (float)h);
        }
    }
    __syncthreads();

    f32x4 acc[NCB];
#pragma unroll
    for (int cb = 0; cb < NCB; ++cb) acc[cb] = f32x4{0.f, 0.f, 0.f, 0.f};
#pragma unroll
    for (int ks = 0; ks < 4; ++ks) {
#pragma unroll
        for (int cb = 0; cb < NCB; ++cb) {
            int wi = (cb * 16 + (l & 15)) * 136 + ks * 32 + kb;
            f16x8 bh = *(const f16x8*)&Hs[wi];
            f16x8 bl = *(const f16x8*)&Ls[wi];
            acc[cb] = __builtin_amdgcn_mfma_f32_16x16x32_f16(ah[ks], bh, acc[cb], 0, 0, 0);
            acc[cb] = __builtin_amdgcn_mfma_f32_16x16x32_f16(ah[ks], bl, acc[cb], 0, 0, 0);
            acc[cb] = __builtin_amdgcn_mfma_f32_16x16x32_f16(al[ks], bh, acc[cb], 0, 0, 0);
        }
    }
    int rbase = r0w + (l >> 4) * 4;
    float dv[4];
#pragma unroll
    for (int i = 0; i < 4; ++i) dv[i] = (rbase + i < N) ? dinv[rbase + i] : 0.f;
#pragma unroll
    for (int cb = 0; cb < NCB; ++cb) {
#pragma unroll
        for (int i = 0; i < 4; ++i) {
            int r = rbase + i;
            if (r < N) A[(long)r * M + c0 + cb * 16 + (l & 15)] = (f16)(acc[cb][i] * dv[i]);
        }
    }
}

// ---------------- GEMM layers 2/3: B fp16 exact, 2 MFMAs, W in LDS ----------------
template<int M>
__global__ __launch_bounds__(256)
void k_gemm23(const f16* __restrict__ B,
              const f16* __restrict__ WTh, const f16* __restrict__ WTl,
              const float* __restrict__ dinv, f16* __restrict__ A, int N) {
    constexpr int NCB = M / 32;
    constexpr int HC = M / 2;
    __shared__ f16 Hs[HC * 136];
    __shared__ f16 Ls[HC * 136];
    int b = blockIdx.x;
    int c0 = (b & 1) * HC;
    int t = threadIdx.x;

#pragma unroll
    for (int i = 0; i < HC / 16; ++i) {
        int ch = t + i * 256;
        int col = ch >> 4;
        int kc = (ch & 15) * 8;
        *(f16x8*)&Hs[col * 136 + kc] = *(const f16x8*)&WTh[(long)(c0 + col) * 128 + kc];
        *(f16x8*)&Ls[col * 136 + kc] = *(const f16x8*)&WTl[(long)(c0 + col) * 128 + kc];
    }

    int wv = t >> 6, l = t & 63;
    int r0w = (b >> 1) * 64 + wv * 16;
    int arow = r0w + (l & 15);
    if (arow >= N) arow = N - 1;
    int kb = (l >> 4) * 8;

    f16x8 a[4];
#pragma unroll
    for (int ks = 0; ks < 4; ++ks)
        a[ks] = *(const f16x8*)&B[(long)arow * 128 + ks * 32 + kb];
    __syncthreads();

    f32x4 acc[NCB];
#pragma unroll
    for (int cb = 0; cb < NCB; ++cb) acc[cb] = f32x4{0.f, 0.f, 0.f, 0.f};
#pragma unroll
    for (int ks = 0; ks < 4; ++ks) {
#pragma unroll
        for (int cb = 0; cb < NCB; ++cb) {
            int wi = (cb * 16 + (l & 15)) * 136 + ks * 32 + kb;
            f16x8 bh = *(const f16x8*)&Hs[wi];
            f16x8 bl = *(const f16x8*)&Ls[wi];
            acc[cb] = __builtin_amdgcn_mfma_f32_16x16x32_f16(a[ks], bh, acc[cb], 0, 0, 0);
            acc[cb] = __builtin_amdgcn_mfma_f32_16x16x32_f16(a[ks], bl, acc[cb], 0, 0, 0);
        }
    }
    int rbase = r0w + (l >> 4) * 4;
    float dv[4];
#pragma unroll
    for (int i = 0; i < 4; ++i) dv[i] = (rbase + i < N) ? dinv[rbase + i] : 0.f;
#pragma unroll
    for (int cb = 0; cb < NCB; ++cb) {
#pragma unroll
        for (int i = 0; i < 4; ++i) {
            int r = rbase + i;
            if (r < N) A[(long)r * M + c0 + cb * 16 + (l & 15)] = (f16)(acc[cb][i] * dv[i]);
        }
    }
}

// ---------------- channel-slice XCD-partitioned gather (M=128, fp16 out) ----------------
// grid = 391*8. g=vb&7: slice cs=g>>1 (32ch=64B line), node-half nh=g&1.
// Per-XCD A-footprint = 50000*64B = 3.2MB < 4MB L2 -> edge reads become L2 hits.
// 4 thr/node x 8ch. Work per edge identical to unsliced version; only locality changes.
__global__ __launch_bounds__(256)
void k_gather128(const f16* __restrict__ A, const int* __restrict__ off,
                 const unsigned short* __restrict__ csr, const float* __restrict__ dinv,
                 const float* __restrict__ bias, f16* __restrict__ Bo) {
    int vb = blockIdx.x;
    int g = vb & 7, blk = vb >> 3;
    int t = threadIdx.x;
    int nl = blk * 64 + (t >> 2);
    if (nl >= 25000) return;
    int node = (g & 1) * 25000 + nl;
    int q = (g >> 1) * 32 + (t & 3) * 8;
    const f16* Aq = A + q;

    float acc[8];
    {
        f16x8 v = *(const f16x8*)&Aq[(long)node * 128];
#pragma unroll
        for (int c = 0; c < 8; ++c) acc[c] = (float)v[c];
    }
    int j = off[node], j1 = off[node + 1];
    for (; j + 8 <= j1; j += 8) {
        int s0 = csr[j + 0], s1 = csr[j + 1], s2 = csr[j + 2], s3 = csr[j + 3];
        int s4 = csr[j + 4], s5 = csr[j + 5], s6 = csr[j + 6], s7 = csr[j + 7];
        f16x8 v0 = *(const f16x8*)&Aq[(long)s0 * 128];
        f16x8 v1 = *(const f16x8*)&Aq[(long)s1 * 128];
        f16x8 v2 = *(const f16x8*)&Aq[(long)s2 * 128];
        f16x8 v3 = *(const f16x8*)&Aq[(long)s3 * 128];
        f16x8 v4 = *(const f16x8*)&Aq[(long)s4 * 128];
        f16x8 v5 = *(const f16x8*)&Aq[(long)s5 * 128];
        f16x8 v6 = *(const f16x8*)&Aq[(long)s6 * 128];
        f16x8 v7 = *(const f16x8*)&Aq[(long)s7 * 128];
#pragma unroll
        for (int c = 0; c < 8; ++c)
            acc[c] += ((float)v0[c] + (float)v1[c] + (float)v2[c] + (float)v3[c])
                    + ((float)v4[c] + (float)v5[c] + (float)v6[c] + (float)v7[c]);
    }
    for (; j + 2 <= j1; j += 2) {
        int s0 = csr[j + 0], s1 = csr[j + 1];
        f16x8 v0 = *(const f16x8*)&Aq[(long)s0 * 128];
        f16x8 v1 = *(const f16x8*)&Aq[(long)s1 * 128];
#pragma unroll
        for (int c = 0; c < 8; ++c) acc[c] += (float)v0[c] + (float)v1[c];
    }
    if (j < j1) {
        int s = csr[j];
        f16x8 v = *(const f16x8*)&Aq[(long)s * 128];
#pragma unroll
        for (int c = 0; c < 8; ++c) acc[c] += (float)v[c];
    }
    float sc = dinv[node];
    float4 bb0 = *(const float4*)&bias[q];
    float4 bb1 = *(const float4*)&bias[q + 4];
    float bv[8] = {bb0.x, bb0.y, bb0.z, bb0.w, bb1.x, bb1.y, bb1.z, bb1.w};
    f16x8 o;
#pragma unroll
    for (int c = 0; c < 8; ++c) o[c] = (f16)fmaxf(acc[c] * sc + bv[c], 0.f);
    *(f16x8*)&Bo[(long)node * 128 + q] = o;
}

// ---------------- channel-slice gather (M=64, fp32 z out, no relu) ----------------
// grid = 196*8. g: slice cs=g&1 (32ch), node-quarter nq=g>>1.
__global__ __launch_bounds__(256)
void k_gather64(const f16* __restrict__ A, const int* __restrict__ off,
                const unsigned short* __restrict__ csr, const float* __restrict__ dinv,
                const float* __restrict__ bias, float* __restrict__ z) {
    int vb = blockIdx.x;
    int g = vb & 7, blk = vb >> 3;
    int t = threadIdx.x;
    int nl = blk * 64 + (t >> 2);
    if (nl >= 12500) return;
    int node = (g >> 1) * 12500 + nl;
    int q = (g & 1) * 32 + (t & 3) * 8;
    const f16* Aq = A + q;

    float acc[8];
    {
        f16x8 v = *(const f16x8*)&Aq[(long)node * 64];
#pragma unroll
        for (int c = 0; c < 8; ++c) acc[c] = (float)v[c];
    }
    int j = off[node], j1 = off[node + 1];
    for (; j + 8 <= j1; j += 8) {
        int s0 = csr[j + 0], s1 = csr[j + 1], s2 = csr[j + 2], s3 = csr[j + 3];
        int s4 = csr[j + 4], s5 = csr[j + 5], s6 = csr[j + 6], s7 = csr[j + 7];
        f16x8 v0 = *(const f16x8*)&Aq[(long)s0 * 64];
        f16x8 v1 = *(const f16x8*)&Aq[(long)s1 * 64];
        f16x8 v2 = *(const f16x8*)&Aq[(long)s2 * 64];
        f16x8 v3 = *(const f16x8*)&Aq[(long)s3 * 64];
        f16x8 v4 = *(const f16x8*)&Aq[(long)s4 * 64];
        f16x8 v5 = *(const f16x8*)&Aq[(long)s5 * 64];
        f16x8 v6 = *(const f16x8*)&Aq[(long)s6 * 64];
        f16x8 v7 = *(const f16x8*)&Aq[(long)s7 * 64];
#pragma unroll
        for (int c = 0; c < 8; ++c)
            acc[c] += ((float)v0[c] + (float)v1[c] + (float)v2[c] + (float)v3[c])
                    + ((float)v4[c] + (float)v5[c] + (float)v6[c] + (float)v7[c]);
    }
    for (; j + 2 <= j1; j += 2) {
        int s0 = csr[j + 0], s1 = csr[j + 1];
        f16x8 v0 = *(const f16x8*)&Aq[(long)s0 * 64];
        f16x8 v1 = *(const f16x8*)&Aq[(long)s1 * 64];
#pragma unroll
        for (int c = 0; c < 8; ++c) acc[c] += (float)v0[c] + (float)v1[c];
    }
    if (j < j1) {
        int s = csr[j];
        f16x8 v = *(const f16x8*)&Aq[(long)s * 64];
#pragma unroll
        for (int c = 0; c < 8; ++c) acc[c] += (float)v[c];
    }
    float sc = dinv[node];
    float4 bb0 = *(const float4*)&bias[q];
    float4 bb1 = *(const float4*)&bias[q + 4];
    float4 o0, o1;
    o0.x = acc[0] * sc + bb0.x; o0.y = acc[1] * sc + bb0.y;
    o0.z = acc[2] * sc + bb0.z; o0.w = acc[3] * sc + bb0.w;
    o1.x = acc[4] * sc + bb1.x; o1.y = acc[5] * sc + bb1.y;
    o1.z = acc[6] * sc + bb1.z; o1.w = acc[7] * sc + bb1.w;
    *(float4*)&z[(long)node * 64 + q] = o0;
    *(float4*)&z[(long)node * 64 + q + 4] = o1;
}

// ---------------- channel-slice decode: partial dots per 16-fp32-ch slice ----------------
// grid = 391*8. g: slice cs=g>>1 (16ch=64B), label-half hh=g&1. P[cs][e] = partial.
__global__ __launch_bounds__(256)
void k_decode_part(const float* __restrict__ z, const int* __restrict__ eli,
                   float* __restrict__ P) {
    int vb = blockIdx.x;
    int g = vb & 7, blk = vb >> 3;
    int el = blk * 256 + threadIdx.x;
    if (el >= 100000) return;
    int e = (g & 1) * 100000 + el;
    int cs = g >> 1;
    const float* za = &z[(long)eli[e] * 64 + cs * 16];
    const float* zb = &z[(long)eli[N_LABEL + e] * 64 + cs * 16];
    float s = 0.f;
#pragma unroll
    for (int i = 0; i < 4; ++i) {
        float4 a = *(const float4*)&za[i * 4];
        float4 b = *(const float4*)&zb[i * 4];
        s += a.x * b.x + a.y * b.y + a.z * b.z + a.w * b.w;
    }
    P[cs * N_LABEL + e] = s;
}

__global__ __launch_bounds__(256)
void k_decode_red(const float* __restrict__ P, float* __restrict__ out) {
    int e = blockIdx.x * 256 + threadIdx.x;
    if (e < N_LABEL)
        out[e] = (P[e] + P[N_LABEL + e]) + (P[2 * N_LABEL + e] + P[3 * N_LABEL + e]);
}

extern "C" void kernel_launch(void* const* d_in, const int* in_sizes, int n_in,
                              void* d_out, int out_size, void* d_ws, size_t ws_size,
                              hipStream_t stream) {
    const float* x   = (const float*)d_in[0];
    const float* W1  = (const float*)d_in[1];
    const float* b1  = (const float*)d_in[2];
    const float* W2  = (const float*)d_in[3];
    const float* b2  = (const float*)d_in[4];
    const float* W3  = (const float*)d_in[5];
    const float* b3  = (const float*)d_in[6];
    const int*   ei  = (const int*)d_in[7];
    const int*   eli = (const int*)d_in[8];
    float* out = (float*)d_out;

    char* ws = (char*)d_ws;
    float* dinv = (float*)ws;                  ws += 50048 * 4;
    f16*   A    = (f16*)ws;                    ws += (long)N_NODES * 128 * 2;
    f16*   B    = (f16*)ws;                    ws += (long)N_NODES * 128 * 2;
    float* z    = (float*)ws;                  ws += (long)N_NODES * 64 * 4;
    float* P    = (float*)ws;                  ws += (long)4 * N_LABEL * 4;
    int*   cnt  = (int*)ws;                    ws += 50048 * 4;
    int*   cnt2 = (int*)ws;                    ws += 50048 * 4;   // contiguous with cnt
    int*   off  = (int*)ws;                    ws += 50048 * 4;
    unsigned short* csr = (unsigned short*)ws; ws += (long)N_EDGES * 2;
    int*   bsum = (int*)ws;                    ws += 256 * 4;
    f16*   WT1h = (f16*)ws;                    ws += 16384 * 2;
    f16*   WT1l = (f16*)ws;                    ws += 16384 * 2;
    f16*   WT2h = (f16*)ws;                    ws += 16384 * 2;
    f16*   WT2l = (f16*)ws;                    ws += 16384 * 2;
    f16*   WT3h = (f16*)ws;                    ws += 8192 * 2;
    f16*   WT3l = (f16*)ws;                    ws += 8192 * 2;

    const int* esrc = ei;
    const int* edst = ei + N_EDGES;

    const int NB = (N_NODES + 255) / 256;  // 196

    k_zero   <<<98, 256, 0, stream>>>((int4*)cnt, 25024);
    k_prep   <<<25064, 256, 0, stream>>>(W1, W2, W3, WT1h, WT1l, WT2h, WT2l,
                                         WT3h, WT3l, edst, cnt);
    k_partial<<<NB, 256, 0, stream>>>(cnt, dinv, bsum, N_NODES);
    k_offsets<<<NB, 256, 0, stream>>>(cnt, bsum, off, N_NODES, NB);
    k_bucket <<<25000, 256, 0, stream>>>(esrc, edst, off, cnt2, csr);

    // layer 1 (x fp32 -> in-register fp16 split; W in LDS; 2-way col split)
    k_gemm1<<<ROW_BLOCKS * 2, 256, 0, stream>>>(x, WT1h, WT1l, dinv, A, N_NODES);
    k_gather128<<<391 * 8, 256, 0, stream>>>(A, off, csr, dinv, b1, B);
    // layer 2
    k_gemm23<128><<<ROW_BLOCKS * 2, 256, 0, stream>>>(B, WT2h, WT2l, dinv, A, N_NODES);
    k_gather128<<<391 * 8, 256, 0, stream>>>(A, off, csr, dinv, b2, B);
    // layer 3 (M=64, no relu, fp32 out)
    k_gemm23<64><<<ROW_BLOCKS * 2, 256, 0, stream>>>(B, WT3h, WT3l, dinv, A, N_NODES);
    k_gather64<<<196 * 8, 256, 0, stream>>>(A, off, csr, dinv, b3, z);

    // decode: channel-sliced partial dots + reduce
    k_decode_part<<<391 * 8, 256, 0, stream>>>(z, eli, P);
    k_decode_red <<<(N_LABEL + 255) / 256, 256, 0, stream>>>(P, out);
}

// Round 14
// 209.807 us; speedup vs baseline: 1.1785x; 1.1785x over previous
//
#include <hip/hip_runtime.h>

#define N_NODES 50000
#define N_EDGES 800000
#define N_LABEL 200000
#define ROW_BLOCKS 782   // ceil(50000/64)

typedef __attribute__((ext_vector_type(4))) float f32x4;
typedef _Float16 f16;
typedef __attribute__((ext_vector_type(8))) _Float16 f16x8;

// Sliced feature layout: X_s[cs][node][32ch] (cs = channel/32). Each 3.2MB slice is
// line-packed -> one XCD's gather working set fits its 4MB L2 (R13 lesson: interleaved
// sub-line slices double-fetch; slices must be physically packed).

// ---------------- zero cnt+cnt2 ----------------
__global__ __launch_bounds__(256)
void k_zero(int4* __restrict__ p, int n4) {
    int i = blockIdx.x * 256 + threadIdx.x;
    if (i < n4) p[i] = int4{0, 0, 0, 0};
}

// ---------------- prep: W transpose/split fp16 hi+lo | XCD-partitioned deg_count ----------
__global__ __launch_bounds__(256)
void k_prep(const float* __restrict__ W1, const float* __restrict__ W2,
            const float* __restrict__ W3,
            f16* WT1h, f16* WT1l, f16* WT2h, f16* WT2l, f16* WT3h, f16* WT3l,
            const int* __restrict__ dst, int* cnt) {
    int b = blockIdx.x, tid = threadIdx.x;
    if (b < 64) {
        int t = b * 256 + tid;                 // < 16384
        int c = t >> 7, k = t & 127;
        float w = W1[k * 128 + c];
        f16 h = (f16)w;
        WT1h[c * 128 + k] = h; WT1l[c * 128 + k] = (f16)(w - (float)h);
        w = W2[k * 128 + c];
        h = (f16)w;
        WT2h[c * 128 + k] = h; WT2l[c * 128 + k] = (f16)(w - (float)h);
        if (c < 64) {
            w = W3[k * 64 + c];
            h = (f16)w;
            WT3h[c * 128 + k] = h; WT3l[c * 128 + k] = (f16)(w - (float)h);
        }
    } else {
        int vb = b - 64;                       // [0, 25000)
        int g = vb & 7;
        int i = (vb >> 3) * 256 + tid;         // < 800,000 exactly
        int d = dst[i];
        if ((unsigned)(d - g * 6250) < 6250u) atomicAdd(&cnt[d], 1);
    }
}

// ---------------- scan chain ----------------
__global__ __launch_bounds__(256)
void k_partial(const int* __restrict__ cnt, float* __restrict__ dinv,
               int* __restrict__ bsum, int N) {
    __shared__ int wsum[4];
    int b = blockIdx.x, t = threadIdx.x;
    int i = b * 256 + t;
    int v = (i < N) ? cnt[i] : 0;
    if (i < N) dinv[i] = rsqrtf((float)v + 1.0f);
    int s = v;
#pragma unroll
    for (int d = 1; d < 64; d <<= 1) s += __shfl_xor(s, d, 64);
    if ((t & 63) == 0) wsum[t >> 6] = s;
    __syncthreads();
    if (t == 0) bsum[b] = wsum[0] + wsum[1] + wsum[2] + wsum[3];
}

__global__ __launch_bounds__(256)
void k_offsets(const int* __restrict__ cnt, const int* __restrict__ bsum,
               int* __restrict__ off, int N, int NB) {
    __shared__ int wsum[4];
    __shared__ int add0_s;
    int b = blockIdx.x, t = threadIdx.x;
    int v0 = (t < b && t < NB) ? bsum[t] : 0;
    int s0 = v0;
#pragma unroll
    for (int d = 1; d < 64; d <<= 1) s0 += __shfl_xor(s0, d, 64);
    if ((t & 63) == 0) wsum[t >> 6] = s0;
    __syncthreads();
    if (t == 0) add0_s = wsum[0] + wsum[1] + wsum[2] + wsum[3];
    __syncthreads();
    int add = add0_s;
    __syncthreads();
    int i = b * 256 + t;
    int v = (i < N) ? cnt[i] : 0;
    int lane = t & 63, w = t >> 6;
    int sv = v;
#pragma unroll
    for (int d = 1; d < 64; d <<= 1) {
        int u = __shfl_up(sv, d, 64);
        if (lane >= d) sv += u;
    }
    if (lane == 63) wsum[w] = sv;
    __syncthreads();
    for (int ww = 0; ww < w; ++ww) add += wsum[ww];
    if (i < N) off[i + 1] = add + sv;
    if (i == 0) off[0] = 0;
}

// ---------------- XCD-partitioned bucket fill ----------------
__global__ __launch_bounds__(256)
void k_bucket(const int* __restrict__ srcv, const int* __restrict__ dstv,
              const int* __restrict__ off, int* cnt2, unsigned short* __restrict__ csr) {
    int vb = blockIdx.x;
    int g = vb & 7;
    int i = (vb >> 3) * 256 + threadIdx.x;   // < 800,000 exactly
    int d = dstv[i];
    if ((unsigned)(d - g * 6250) < 6250u) {
        int slot = off[d] + atomicAdd(&cnt2[d], 1);
        csr[slot] = (unsigned short)srcv[i];
    }
}

// ---------------- GEMM layer 1: fp32 x, in-register fp16 split, W in LDS, sliced out ----
__global__ __launch_bounds__(256)
void k_gemm1(const float* __restrict__ x,
             const f16* __restrict__ WTh, const f16* __restrict__ WTl,
             const float* __restrict__ dinv, f16* __restrict__ As, int N) {
    constexpr int NCB = 4;
    __shared__ f16 Hs[64 * 136];
    __shared__ f16 Ls[64 * 136];
    int b = blockIdx.x;
    int c0 = (b & 1) * 64;
    int t = threadIdx.x;

#pragma unroll
    for (int i = 0; i < 4; ++i) {
        int ch = t + i * 256;
        int col = ch >> 4;
        int kc = (ch & 15) * 8;
        *(f16x8*)&Hs[col * 136 + kc] = *(const f16x8*)&WTh[(long)(c0 + col) * 128 + kc];
        *(f16x8*)&Ls[col * 136 + kc] = *(const f16x8*)&WTl[(long)(c0 + col) * 128 + kc];
    }

    int wv = t >> 6, l = t & 63;
    int r0w = (b >> 1) * 64 + wv * 16;
    int arow = r0w + (l & 15);
    if (arow >= N) arow = N - 1;
    int kb = (l >> 4) * 8;

    f16x8 ah[4], al[4];
#pragma unroll
    for (int ks = 0; ks < 4; ++ks) {
        const float* xp = &x[(long)arow * 128 + ks * 32 + kb];
        float4 a0 = *(const float4*)xp;
        float4 a1 = *(const float4*)(xp + 4);
        float fv[8] = {a0.x, a0.y, a0.z, a0.w, a1.x, a1.y, a1.z, a1.w};
#pragma unroll
        for (int j = 0; j < 8; ++j) {
            f16 h = (f16)fv[j];
            ah[ks][j] = h;
            al[ks][j] = (f16)(fv[j] - (float)h);
        }
    }
    __syncthreads();

    f32x4 acc[NCB];
#pragma unroll
    for (int cb = 0; cb < NCB; ++cb) acc[cb] = f32x4{0.f, 0.f, 0.f, 0.f};
#pragma unroll
    for (int ks = 0; ks < 4; ++ks) {
#pragma unroll
        for (int cb = 0; cb < NCB; ++cb) {
            int wi = (cb * 16 + (l & 15)) * 136 + ks * 32 + kb;
            f16x8 bh = *(const f16x8*)&Hs[wi];
            f16x8 bl = *(const f16x8*)&Ls[wi];
            acc[cb] = __builtin_amdgcn_mfma_f32_16x16x32_f16(ah[ks], bh, acc[cb], 0, 0, 0);
            acc[cb] = __builtin_amdgcn_mfma_f32_16x16x32_f16(ah[ks], bl, acc[cb], 0, 0, 0);
            acc[cb] = __builtin_amdgcn_mfma_f32_16x16x32_f16(al[ks], bh, acc[cb], 0, 0, 0);
        }
    }
    int rbase = r0w + (l >> 4) * 4;
    float dv[4];
#pragma unroll
    for (int i = 0; i < 4; ++i) dv[i] = (rbase + i < N) ? dinv[rbase + i] : 0.f;
#pragma unroll
    for (int cb = 0; cb < NCB; ++cb) {
        int fc = c0 + cb * 16 + (l & 15);          // full channel 0..127
        long sb = (long)(fc >> 5) * N_NODES * 32 + (fc & 31);
#pragma unroll
        for (int i = 0; i < 4; ++i) {
            int r = rbase + i;
            if (r < N) As[sb + (long)r * 32] = (f16)(acc[cb][i] * dv[i]);
        }
    }
}

// ---------------- GEMM layers 2/3: B_s sliced in, 2 MFMAs, W in LDS, sliced out --------
template<int M>
__global__ __launch_bounds__(256)
void k_gemm23(const f16* __restrict__ Bs,
              const f16* __restrict__ WTh, const f16* __restrict__ WTl,
              const float* __restrict__ dinv, f16* __restrict__ As, int N) {
    constexpr int NCB = M / 32;
    constexpr int HC = M / 2;
    __shared__ f16 Hs[HC * 136];
    __shared__ f16 Ls[HC * 136];
    int b = blockIdx.x;
    int c0 = (b & 1) * HC;
    int t = threadIdx.x;

#pragma unroll
    for (int i = 0; i < HC / 16; ++i) {
        int ch = t + i * 256;
        int col = ch >> 4;
        int kc = (ch & 15) * 8;
        *(f16x8*)&Hs[col * 136 + kc] = *(const f16x8*)&WTh[(long)(c0 + col) * 128 + kc];
        *(f16x8*)&Ls[col * 136 + kc] = *(const f16x8*)&WTl[(long)(c0 + col) * 128 + kc];
    }

    int wv = t >> 6, l = t & 63;
    int r0w = (b >> 1) * 64 + wv * 16;
    int arow = r0w + (l & 15);
    if (arow >= N) arow = N - 1;
    int kb = (l >> 4) * 8;

    // input row channels [ks*32+kb, +8) live in slice ks of Bs (kb < 32)
    f16x8 a[4];
#pragma unroll
    for (int ks = 0; ks < 4; ++ks)
        a[ks] = *(const f16x8*)&Bs[((long)ks * N_NODES + arow) * 32 + kb];
    __syncthreads();

    f32x4 acc[NCB];
#pragma unroll
    for (int cb = 0; cb < NCB; ++cb) acc[cb] = f32x4{0.f, 0.f, 0.f, 0.f};
#pragma unroll
    for (int ks = 0; ks < 4; ++ks) {
#pragma unroll
        for (int cb = 0; cb < NCB; ++cb) {
            int wi = (cb * 16 + (l & 15)) * 136 + ks * 32 + kb;
            f16x8 bh = *(const f16x8*)&Hs[wi];
            f16x8 bl = *(const f16x8*)&Ls[wi];
            acc[cb] = __builtin_amdgcn_mfma_f32_16x16x32_f16(a[ks], bh, acc[cb], 0, 0, 0);
            acc[cb] = __builtin_amdgcn_mfma_f32_16x16x32_f16(a[ks], bl, acc[cb], 0, 0, 0);
        }
    }
    int rbase = r0w + (l >> 4) * 4;
    float dv[4];
#pragma unroll
    for (int i = 0; i < 4; ++i) dv[i] = (rbase + i < N) ? dinv[rbase + i] : 0.f;
#pragma unroll
    for (int cb = 0; cb < NCB; ++cb) {
        int fc = c0 + cb * 16 + (l & 15);          // 0..M-1
        long sb = (long)(fc >> 5) * N_NODES * 32 + (fc & 31);
#pragma unroll
        for (int i = 0; i < 4; ++i) {
            int r = rbase + i;
            if (r < N) As[sb + (long)r * 32] = (f16)(acc[cb][i] * dv[i]);
        }
    }
}

// ---------------- sliced XCD-partitioned gather (M=128): A_s -> B_s ----------------
// grid = 391*8. g=vb&7: slice cs=g>>1, node-half nh=g&1. 4 thr/node x 8ch.
// Per-XCD read set = A_s[cs] = 3.2MB (line-packed) -> L2-resident.
__global__ __launch_bounds__(256)
void k_gather128(const f16* __restrict__ As, const int* __restrict__ off,
                 const unsigned short* __restrict__ csr, const float* __restrict__ dinv,
                 const float* __restrict__ bias, f16* __restrict__ Bs) {
    int vb = blockIdx.x;
    int g = vb & 7, blk = vb >> 3;
    int t = threadIdx.x;
    int nl = blk * 64 + (t >> 2);
    if (nl >= 25000) return;
    int node = (g & 1) * 25000 + nl;
    int cs = g >> 1;
    int qq = (t & 3) * 8;                       // within-slice channel
    const f16* Aq = As + (long)cs * N_NODES * 32 + qq;

    float acc[8];
    {
        f16x8 v = *(const f16x8*)&Aq[(long)node * 32];
#pragma unroll
        for (int c = 0; c < 8; ++c) acc[c] = (float)v[c];
    }
    int j = off[node], j1 = off[node + 1];
    for (; j + 8 <= j1; j += 8) {
        int s0 = csr[j + 0], s1 = csr[j + 1], s2 = csr[j + 2], s3 = csr[j + 3];
        int s4 = csr[j + 4], s5 = csr[j + 5], s6 = csr[j + 6], s7 = csr[j + 7];
        f16x8 v0 = *(const f16x8*)&Aq[(long)s0 * 32];
        f16x8 v1 = *(const f16x8*)&Aq[(long)s1 * 32];
        f16x8 v2 = *(const f16x8*)&Aq[(long)s2 * 32];
        f16x8 v3 = *(const f16x8*)&Aq[(long)s3 * 32];
        f16x8 v4 = *(const f16x8*)&Aq[(long)s4 * 32];
        f16x8 v5 = *(const f16x8*)&Aq[(long)s5 * 32];
        f16x8 v6 = *(const f16x8*)&Aq[(long)s6 * 32];
        f16x8 v7 = *(const f16x8*)&Aq[(long)s7 * 32];
#pragma unroll
        for (int c = 0; c < 8; ++c)
            acc[c] += ((float)v0[c] + (float)v1[c] + (float)v2[c] + (float)v3[c])
                    + ((float)v4[c] + (float)v5[c] + (float)v6[c] + (float)v7[c]);
    }
    for (; j + 2 <= j1; j += 2) {
        int s0 = csr[j + 0], s1 = csr[j + 1];
        f16x8 v0 = *(const f16x8*)&Aq[(long)s0 * 32];
        f16x8 v1 = *(const f16x8*)&Aq[(long)s1 * 32];
#pragma unroll
        for (int c = 0; c < 8; ++c) acc[c] += (float)v0[c] + (float)v1[c];
    }
    if (j < j1) {
        int s = csr[j];
        f16x8 v = *(const f16x8*)&Aq[(long)s * 32];
#pragma unroll
        for (int c = 0; c < 8; ++c) acc[c] += (float)v[c];
    }
    float sc = dinv[node];
    int q = cs * 32 + qq;
    float4 bb0 = *(const float4*)&bias[q];
    float4 bb1 = *(const float4*)&bias[q + 4];
    float bv[8] = {bb0.x, bb0.y, bb0.z, bb0.w, bb1.x, bb1.y, bb1.z, bb1.w};
    f16x8 o;
#pragma unroll
    for (int c = 0; c < 8; ++c) o[c] = (f16)fmaxf(acc[c] * sc + bv[c], 0.f);
    *(f16x8*)&Bs[((long)cs * N_NODES + node) * 32 + qq] = o;
}

// ---------------- sliced gather (M=64): A3_s (2 slices) -> z fp32, no relu ----------
// grid = 196*8. g: slice cs=g&1, node-quarter nq=g>>1. 4 thr/node x 8ch.
__global__ __launch_bounds__(256)
void k_gather64(const f16* __restrict__ As, const int* __restrict__ off,
                const unsigned short* __restrict__ csr, const float* __restrict__ dinv,
                const float* __restrict__ bias, float* __restrict__ z) {
    int vb = blockIdx.x;
    int g = vb & 7, blk = vb >> 3;
    int t = threadIdx.x;
    int nl = blk * 64 + (t >> 2);
    if (nl >= 12500) return;
    int node = (g >> 1) * 12500 + nl;
    int cs = g & 1;
    int qq = (t & 3) * 8;
    const f16* Aq = As + (long)cs * N_NODES * 32 + qq;

    float acc[8];
    {
        f16x8 v = *(const f16x8*)&Aq[(long)node * 32];
#pragma unroll
        for (int c = 0; c < 8; ++c) acc[c] = (float)v[c];
    }
    int j = off[node], j1 = off[node + 1];
    for (; j + 8 <= j1; j += 8) {
        int s0 = csr[j + 0], s1 = csr[j + 1], s2 = csr[j + 2], s3 = csr[j + 3];
        int s4 = csr[j + 4], s5 = csr[j + 5], s6 = csr[j + 6], s7 = csr[j + 7];
        f16x8 v0 = *(const f16x8*)&Aq[(long)s0 * 32];
        f16x8 v1 = *(const f16x8*)&Aq[(long)s1 * 32];
        f16x8 v2 = *(const f16x8*)&Aq[(long)s2 * 32];
        f16x8 v3 = *(const f16x8*)&Aq[(long)s3 * 32];
        f16x8 v4 = *(const f16x8*)&Aq[(long)s4 * 32];
        f16x8 v5 = *(const f16x8*)&Aq[(long)s5 * 32];
        f16x8 v6 = *(const f16x8*)&Aq[(long)s6 * 32];
        f16x8 v7 = *(const f16x8*)&Aq[(long)s7 * 32];
#pragma unroll
        for (int c = 0; c < 8; ++c)
            acc[c] += ((float)v0[c] + (float)v1[c] + (float)v2[c] + (float)v3[c])
                    + ((float)v4[c] + (float)v5[c] + (float)v6[c] + (float)v7[c]);
    }
    for (; j + 2 <= j1; j += 2) {
        int s0 = csr[j + 0], s1 = csr[j + 1];
        f16x8 v0 = *(const f16x8*)&Aq[(long)s0 * 32];
        f16x8 v1 = *(const f16x8*)&Aq[(long)s1 * 32];
#pragma unroll
        for (int c = 0; c < 8; ++c) acc[c] += (float)v0[c] + (float)v1[c];
    }
    if (j < j1) {
        int s = csr[j];
        f16x8 v = *(const f16x8*)&Aq[(long)s * 32];
#pragma unroll
        for (int c = 0; c < 8; ++c) acc[c] += (float)v[c];
    }
    float sc = dinv[node];
    int q = cs * 32 + qq;
    float4 bb0 = *(const float4*)&bias[q];
    float4 bb1 = *(const float4*)&bias[q + 4];
    float4 o0, o1;
    o0.x = acc[0] * sc + bb0.x; o0.y = acc[1] * sc + bb0.y;
    o0.z = acc[2] * sc + bb0.z; o0.w = acc[3] * sc + bb0.w;
    o1.x = acc[4] * sc + bb1.x; o1.y = acc[5] * sc + bb1.y;
    o1.z = acc[6] * sc + bb1.z; o1.w = acc[7] * sc + bb1.w;
    *(float4*)&z[(long)node * 64 + q] = o0;
    *(float4*)&z[(long)node * 64 + q + 4] = o1;
}

// ---------------- decode: out[i] = dot64(z[a], z[b]) (R12 form) ----------------
__global__ void k_decode(const float* __restrict__ z, const int* __restrict__ eli,
                         float* __restrict__ out, int L) {
    int t = blockIdx.x * blockDim.x + threadIdx.x;
    int e = t >> 4;
    int lane = t & 15;
    if (e >= L) return;
    int a = eli[e], b = eli[L + e];
    float4 va = *(const float4*)&z[(long)a * 64 + lane * 4];
    float4 vb = *(const float4*)&z[(long)b * 64 + lane * 4];
    float s = va.x * vb.x + va.y * vb.y + va.z * vb.z + va.w * vb.w;
    s += __shfl_xor(s, 1, 16);
    s += __shfl_xor(s, 2, 16);
    s += __shfl_xor(s, 4, 16);
    s += __shfl_xor(s, 8, 16);
    if (lane == 0) out[e] = s;
}

extern "C" void kernel_launch(void* const* d_in, const int* in_sizes, int n_in,
                              void* d_out, int out_size, void* d_ws, size_t ws_size,
                              hipStream_t stream) {
    const float* x   = (const float*)d_in[0];
    const float* W1  = (const float*)d_in[1];
    const float* b1  = (const float*)d_in[2];
    const float* W2  = (const float*)d_in[3];
    const float* b2  = (const float*)d_in[4];
    const float* W3  = (const float*)d_in[5];
    const float* b3  = (const float*)d_in[6];
    const int*   ei  = (const int*)d_in[7];
    const int*   eli = (const int*)d_in[8];
    float* out = (float*)d_out;

    char* ws = (char*)d_ws;
    float* dinv = (float*)ws;                  ws += 50048 * 4;
    f16*   A    = (f16*)ws;                    ws += (long)N_NODES * 128 * 2;   // sliced
    f16*   B    = (f16*)ws;                    ws += (long)N_NODES * 128 * 2;   // sliced
    float* z    = (float*)ws;                  ws += (long)N_NODES * 64 * 4;
    int*   cnt  = (int*)ws;                    ws += 50048 * 4;
    int*   cnt2 = (int*)ws;                    ws += 50048 * 4;   // contiguous with cnt
    int*   off  = (int*)ws;                    ws += 50048 * 4;
    unsigned short* csr = (unsigned short*)ws; ws += (long)N_EDGES * 2;
    int*   bsum = (int*)ws;                    ws += 256 * 4;
    f16*   WT1h = (f16*)ws;                    ws += 16384 * 2;
    f16*   WT1l = (f16*)ws;                    ws += 16384 * 2;
    f16*   WT2h = (f16*)ws;                    ws += 16384 * 2;
    f16*   WT2l = (f16*)ws;                    ws += 16384 * 2;
    f16*   WT3h = (f16*)ws;                    ws += 8192 * 2;
    f16*   WT3l = (f16*)ws;                    ws += 8192 * 2;

    const int* esrc = ei;
    const int* edst = ei + N_EDGES;

    const int NB = (N_NODES + 255) / 256;  // 196

    k_zero   <<<98, 256, 0, stream>>>((int4*)cnt, 25024);
    k_prep   <<<25064, 256, 0, stream>>>(W1, W2, W3, WT1h, WT1l, WT2h, WT2l,
                                         WT3h, WT3l, edst, cnt);
    k_partial<<<NB, 256, 0, stream>>>(cnt, dinv, bsum, N_NODES);
    k_offsets<<<NB, 256, 0, stream>>>(cnt, bsum, off, N_NODES, NB);
    k_bucket <<<25000, 256, 0, stream>>>(esrc, edst, off, cnt2, csr);

    // layer 1
    k_gemm1<<<ROW_BLOCKS * 2, 256, 0, stream>>>(x, WT1h, WT1l, dinv, A, N_NODES);
    k_gather128<<<391 * 8, 256, 0, stream>>>(A, off, csr, dinv, b1, B);
    // layer 2
    k_gemm23<128><<<ROW_BLOCKS * 2, 256, 0, stream>>>(B, WT2h, WT2l, dinv, A, N_NODES);
    k_gather128<<<391 * 8, 256, 0, stream>>>(A, off, csr, dinv, b2, B);
    // layer 3 (M=64, 2 slices, no relu, fp32 z out)
    k_gemm23<64><<<ROW_BLOCKS * 2, 256, 0, stream>>>(B, WT3h, WT3l, dinv, A, N_NODES);
    k_gather64<<<196 * 8, 256, 0, stream>>>(A, off, csr, dinv, b3, z);

    // decode
    k_decode<<<(N_LABEL * 16 + 255) / 256, 256, 0, stream>>>(z, eli, out, N_LABEL);
}